// Round 1
// 607.729 us; speedup vs baseline: 1.0911x; 1.0911x over previous
//
#include <hip/hip_runtime.h>
#include <math.h>

typedef _Float16 f16x8 __attribute__((ext_vector_type(8)));
typedef float f32x16 __attribute__((ext_vector_type(16)));
typedef unsigned int uint4v __attribute__((ext_vector_type(4)));

namespace {
constexpr int LDIM = 26;
constexpr int KDIM = 64;
constexpr int NSAMP = 262144;
constexpr int NITER = 8;
constexpr float WFLOOR = 1e-5f;
constexpr float VFLOOR = 1e-6f;
constexpr float LOG2PI_TERM = 47.784803726642976f;  // 26 * ln(2*pi)
constexpr float L2E = 1.44269504088896340736f;
constexpr float LN2 = 0.69314718055994530942f;

constexpr int ACC_STRIDE = 53;                       // z, px[26], pxx[26]
constexpr int ACC_N = KDIM * ACC_STRIDE + 1;         // 3393 (last = ll)
constexpr int NCOPIES = 8;
constexpr int WROW = 36;                             // dwords per coef row
constexpr int NBLK = 1024;                           // 4 waves = 2 pairs; 256 samples/block
constexpr int PART_STRIDE = 3408;
}

// Static device storage: removes all dependence on the harness workspace so the
// partial-store reduction path ALWAYS runs (no device-scope fp atomics, which
// on multi-XCD parts execute at the fabric coherence point, not in L2).
__device__ float g_partial[NBLK * PART_STRIDE];                         // ~14 MB
__device__ float g_accum[NCOPIES * ACC_N];                              // 108 KB
__device__ float g_w[KDIM];
__device__ float g_mu[KDIM * LDIM];
__device__ float g_sig[KDIM * LDIM];
__device__ float g_ll[1];
__device__ __align__(16) unsigned g_coef[KDIM * WROW];                  // f16-pair coef rows

__device__ __forceinline__ unsigned pkrtz(float a, float b) {
  return __builtin_bit_cast(unsigned, __builtin_amdgcn_cvt_pkrtz(a, b));
}
__device__ __forceinline__ f16x8 ld8h(const unsigned* p) {
  uint4v v = *(const uint4v*)p;
  return __builtin_bit_cast(f16x8, v);
}
__device__ __forceinline__ f32x16 mfma16(f16x8 a, f16x8 b, f32x16 c) {
  return __builtin_amdgcn_mfma_f32_32x32x16_f16(a, b, c, 0, 0, 0);
}

// Coef row k (f16 pairs, 36-dword rows): slots 0..25 = -0.5/sig, 26..51 = mu/sig,
// 52 = C, 53 = C - f16(C) (split constant), rest 0.
__device__ void pack_row(int k, float w, const float* mu, const float* sg, unsigned* wp) {
  float A[LDIM], Bv[LDIM];
  float logdet = 0.f, q = 0.f;
#pragma unroll
  for (int l = 0; l < LDIM; ++l) {
    float pr = 1.0f / sg[l];
    logdet += __logf(sg[l]);
    A[l] = -0.5f * pr;
    Bv[l] = mu[l] * pr;
    q = __builtin_fmaf(mu[l] * mu[l], pr, q);
  }
  float C = __logf(w) - 0.5f * (LOG2PI_TERM + logdet + q);
  float Chi = (float)__builtin_amdgcn_cvt_pkrtz(C, 0.0f)[0];
  float Clo = C - Chi;
  unsigned* row = wp + k * WROW;
#define CF(f) ((f) < 26 ? A[(f)] : (f) < 52 ? Bv[(f) - 26] : (f) == 52 ? C : (f) == 53 ? Clo : 0.0f)
#pragma unroll
  for (int D = 0; D < 32; ++D) row[D] = pkrtz(CF(2 * D), CF(2 * D + 1));
#undef CF
#pragma unroll
  for (int D = 32; D < 36; ++D) row[D] = 0u;
}

__global__ void prep_coef(const float* __restrict__ w0, const float* __restrict__ mu0,
                          const float* __restrict__ sig0) {
  const int k = threadIdx.x;  // 64 threads
  float wv = w0[k];
  float s = wv;
#pragma unroll
  for (int d = 1; d < 64; d <<= 1) s += __shfl_xor(s, d, 64);
  float w = wv / s;
  float mu[LDIM], sg[LDIM];
#pragma unroll
  for (int l = 0; l < LDIM; ++l) {
    mu[l] = mu0[k * LDIM + l];
    sg[l] = sig0[k * LDIM + l];
  }
  pack_row(k, w, mu, sg, g_coef);
}

// k-split wave pairs: 4 waves/block = 2 pairs; within a pair, wave kh owns
// components [kh*32, kh*32+32). Pair shares XT/SQT (double-buffered); softmax
// max/sum over all 64 k via a SINGLE-barrier (m,s) pair exchange per tile.
__global__ __launch_bounds__(256, 4) void em_mfma(const float* __restrict__ x) {
  __shared__ __align__(16) unsigned char xtbuf[2][2][2][2048];  // [pair][buf][XT|SQT]
  __shared__ __align__(16) unsigned char ptbuf[4][2048];        // per-wave P^T (32x32 f16)
  __shared__ float2 exch[2][2][2][32];                          // [buf][pair][kh][sl] = (m,s)

  const int tid = threadIdx.x;
  const int lane = tid & 63;
  const int warp = tid >> 6;
  const int pair = warp >> 1;
  const int kh = warp & 1;
  const int sl = lane & 31;
  const int h = lane >> 5;

  unsigned short* PTs = (unsigned short*)&ptbuf[warp][0];
  const unsigned* PTd = (const unsigned*)&ptbuf[warp][0];

  f32x16 aX = {0,0,0,0,0,0,0,0,0,0,0,0,0,0,0,0};
  f32x16 aQ = {0,0,0,0,0,0,0,0,0,0,0,0,0,0,0,0};
  float llacc = 0.f;

  const int sbase = blockIdx.x * 256 + pair * 128;
  const int rowbase = (kh * 32 + sl) * WROW;

  float xv[LDIM];
  {
    const float2* xp = (const float2*)(x + (size_t)(sbase + sl) * LDIM);
#pragma unroll
    for (int j = 0; j < 13; ++j) {
      float2 v = xp[j];
      xv[2 * j] = v.x;
      xv[2 * j + 1] = v.y;
    }
  }

#pragma unroll
  for (int t = 0; t < 4; ++t) {
    // ---- pack sample to f16 pairs: xh (x), sq (x^2, rounded from f32) ----
    unsigned xhu[13], squ[13];
#pragma unroll
    for (int j = 0; j < 13; ++j) {
      xhu[j] = pkrtz(xv[2 * j], xv[2 * j + 1]);
      squ[j] = pkrtz(xv[2 * j] * xv[2 * j], xv[2 * j + 1] * xv[2 * j + 1]);
    }
    // ---- prefetch next tile's sample ----
    if (t < 3) {
      const float2* xp = (const float2*)(x + (size_t)(sbase + (t + 1) * 32 + sl) * LDIM);
#pragma unroll
      for (int j = 0; j < 13; ++j) {
        float2 v = xp[j];
        xv[2 * j] = v.x;
        xv[2 * j + 1] = v.y;
      }
    }
    // ---- scatter transposes into pair-shared buffers (kh0: XT, kh1: SQT) ----
    unsigned short* XTs = (unsigned short*)&xtbuf[pair][t & 1][0][0];
    unsigned short* SQs = (unsigned short*)&xtbuf[pair][t & 1][1][0];
    {
      unsigned short* Ts = kh ? SQs : XTs;
#pragma unroll
      for (int c = 0; c < LDIM; ++c) {
        unsigned v = (c & 1) ? ((kh ? squ[c >> 1] : xhu[c >> 1]) >> 16)
                             : ((kh ? squ[c >> 1] : xhu[c >> 1]) & 0xffffu);
        Ts[(c * 32 + sl) ^ ((c & 7) << 3)] = (unsigned short)v;
      }
      Ts[(26 * 32 + sl) ^ ((26 & 7) << 3)] = kh ? (unsigned short)0 : (unsigned short)0x3C00;
    }

    // ---- E GEMM: e[k_local, s] for own k-half; coefs straight from global ----
    f16x8 ca[4];
#pragma unroll
    for (int q = 0; q < 4; ++q) ca[q] = ld8h(g_coef + rowbase + 8 * q + 4 * h);

    f32x16 e = {0,0,0,0,0,0,0,0,0,0,0,0,0,0,0,0};
    {
      uint4v b0 = {h ? squ[4] : squ[0], h ? squ[5] : squ[1],
                   h ? squ[6] : squ[2], h ? squ[7] : squ[3]};
      e = mfma16(ca[0], __builtin_bit_cast(f16x8, b0), e);
      uint4v b1 = {h ? squ[12] : squ[8], h ? xhu[0] : squ[9],
                   h ? xhu[1] : squ[10], h ? xhu[2] : squ[11]};
      e = mfma16(ca[1], __builtin_bit_cast(f16x8, b1), e);
      uint4v b2 = {h ? xhu[7] : xhu[3], h ? xhu[8] : xhu[4],
                   h ? xhu[9] : xhu[5], h ? xhu[10] : xhu[6]};
      e = mfma16(ca[2], __builtin_bit_cast(f16x8, b2), e);
      uint4v b3 = {h ? 0u : xhu[11], h ? 0u : xhu[12],
                   h ? 0u : 0x3C003C00u, 0u};
      e = mfma16(ca[3], __builtin_bit_cast(f16x8, b3), e);
    }

    // ---- softmax over all 64 k: in-lane tree + cross-half shfl + ONE-barrier
    //      (m,s) pair exchange: each half exponentiates vs its own max, then
    //      rescales by exp(mh - M) after seeing the partner's (m,s). ----
    float m8[8];
#pragma unroll
    for (int r = 0; r < 8; ++r) m8[r] = fmaxf(e[r], e[r + 8]);
#pragma unroll
    for (int d = 4; d > 0; d >>= 1)
#pragma unroll
      for (int r = 0; r < d; ++r) m8[r] = fmaxf(m8[r], m8[r + d]);
    float mh = fmaxf(m8[0], __shfl_xor(m8[0], 32));     // max over own 32 k
    const float mhL = mh * L2E;
#pragma unroll
    for (int r = 0; r < 16; ++r)
      e[r] = __builtin_amdgcn_exp2f(__builtin_fmaf(e[r], L2E, -mhL));
    float s8[8];
#pragma unroll
    for (int r = 0; r < 8; ++r) s8[r] = e[r] + e[r + 8];
#pragma unroll
    for (int d = 4; d > 0; d >>= 1)
#pragma unroll
      for (int r = 0; r < d; ++r) s8[r] += s8[r + d];
    float sh = s8[0] + __shfl_xor(s8[0], 32);           // sum exp(e - mh) over own 32 k
    exch[t & 1][pair][kh][sl] = make_float2(mh, sh);
    __syncthreads();
    float2 o = exch[t & 1][pair][kh ^ 1][sl];
    float M = fmaxf(mh, o.x);
    float eh = __builtin_amdgcn_exp2f((mh - M) * L2E);
    float eo = __builtin_amdgcn_exp2f((o.x - M) * L2E);
    float SS = __builtin_fmaf(sh, eh, o.y * eo);
    const float scale = eh * __builtin_amdgcn_rcpf(SS);
    if (kh == 0) llacc += M + __builtin_amdgcn_logf(SS) * LN2;  // counted by both lane-halves

    // ---- P^T scatter (own k-half rows; D-row mapping m74/m101) ----
#pragma unroll
    for (int r = 0; r < 16; ++r) {
      const int row = (r & 3) + 8 * (r >> 2) + 4 * h;
      _Float16 pv = (_Float16)(e[r] * scale);
      PTs[(row * 32 + sl) ^ ((row & 7) << 3)] = __builtin_bit_cast(unsigned short, pv);
    }

    // ---- M GEMM: aX += P.X^T (col26 -> z), aQ += P.SQ^T ----
    const unsigned* XTd = (const unsigned*)XTs;
    const unsigned* SQd = (const unsigned*)SQs;
#pragma unroll
    for (int ks = 0; ks < 2; ++ks) {
      const int off = 8 * ks + 4 * h;
      const int swz = (sl & 7) << 2;
      f16x8 a  = ld8h(&PTd[(sl * 16 + off) ^ swz]);
      f16x8 bx = ld8h(&XTd[(sl * 16 + off) ^ swz]);
      f16x8 bq = ld8h(&SQd[(sl * 16 + off) ^ swz]);
      aX = mfma16(a, bx, aX);
      aQ = mfma16(a, bq, aQ);
    }
  }

  // ---- epilogue: block reduce in LDS, then partial store (no global atomics) ----
  __syncthreads();
  float* red = (float*)&xtbuf[0][0][0][0];  // 3393 floats overlaying dead buffers
  for (int i = tid; i < ACC_N; i += 256) red[i] = 0.f;
  __syncthreads();
#pragma unroll
  for (int r = 0; r < 16; ++r) {
    const int row = kh * 32 + (r & 3) + 8 * (r >> 2) + 4 * h;
    const int n = sl;
    if (n < 26) {
      atomicAdd(&red[row * ACC_STRIDE + 1 + n], aX[r]);
      atomicAdd(&red[row * ACC_STRIDE + 27 + n], aQ[r]);
    } else if (n == 26) {
      atomicAdd(&red[row * ACC_STRIDE], aX[r]);
    }
  }
  float llw = llacc * 0.5f;  // each sample counted by both lane-halves of the kh0 wave
#pragma unroll
  for (int d = 1; d < 64; d <<= 1) llw += __shfl_xor(llw, d, 64);
  if (lane == 0 && kh == 0) atomicAdd(&red[KDIM * ACC_STRIDE], llw);
  __syncthreads();
  float* pb = g_partial + (size_t)blockIdx.x * PART_STRIDE;
  for (int i = tid; i < ACC_N; i += 256) pb[i] = red[i];
}

// fold 1024 block-partials into 8 accumulator copies (plain stores, no atomics)
__global__ void reduce_partials() {
  const int i = blockIdx.x * 64 + threadIdx.x;
  if (i >= ACC_N) return;
  const int cy = blockIdx.y;  // 8 chunks of 128 blocks
  const float* p = g_partial + (size_t)cy * 128 * PART_STRIDE + i;
  float s = 0.f;
#pragma unroll 8
  for (int j = 0; j < 128; ++j) s += p[(size_t)j * PART_STRIDE];
  g_accum[cy * ACC_N + i] = s;
}

__global__ void finalize_k() {
  const int k = threadIdx.x;  // 64 threads
  float vals[ACC_STRIDE];
#pragma unroll
  for (int j = 0; j < ACC_STRIDE; ++j) vals[j] = 0.f;
  float llsum = 0.f;
  for (int cp = 0; cp < NCOPIES; ++cp) {
    const float* a = g_accum + cp * ACC_N;
#pragma unroll
    for (int j = 0; j < ACC_STRIDE; ++j) vals[j] += a[k * ACC_STRIDE + j];
    llsum += a[KDIM * ACC_STRIDE];
  }
  float z = vals[0];
  float wn = z * (1.0f / NSAMP);
  float wf = fmaxf(wn, WFLOOR);
  float S = wf;
#pragma unroll
  for (int d = 1; d < 64; d <<= 1) S += __shfl_xor(S, d, 64);
  const float sf = WFLOOR * KDIM;
  float a = (1.0f - sf) / (S - sf);
  float b = WFLOOR * (1.0f - a);
  float w = a * wf + b;
  g_w[k] = w;
  float zinv = 1.0f / z;
  float muk[LDIM], sgk[LDIM];
#pragma unroll
  for (int l = 0; l < LDIM; ++l) {
    float m = vals[1 + l] * zinv;
    float s2 = fmaxf(__builtin_fmaf(-m, m, vals[27 + l] * zinv), VFLOOR);
    muk[l] = m;
    sgk[l] = s2;
    g_mu[k * LDIM + l] = m;
    g_sig[k * LDIM + l] = s2;
  }
  if (k == 0) g_ll[0] = llsum;
  pack_row(k, w, muk, sgk, g_coef);
}

__global__ void writeout(float* __restrict__ out) {
  const int i = blockIdx.x * 256 + threadIdx.x;
  // out: w[64] | mu[64*26] | sigma[64*26*26] (diag) | ll[1]
  if (i < 64) {
    out[i] = g_w[i];
  } else if (i < 64 + KDIM * LDIM) {
    out[i] = g_mu[i - 64];
  } else if (i < 64 + KDIM * LDIM + KDIM * LDIM * LDIM) {
    int t = i - (64 + KDIM * LDIM);
    int k = t / (LDIM * LDIM);
    int r = t % (LDIM * LDIM);
    int ii = r / LDIM;
    int jj = r % LDIM;
    out[i] = (ii == jj) ? g_sig[k * LDIM + ii] : 0.f;
  } else if (i == 64 + KDIM * LDIM + KDIM * LDIM * LDIM) {
    out[i] = g_ll[0];
  }
}

extern "C" void kernel_launch(void* const* d_in, const int* in_sizes, int n_in,
                              void* d_out, int out_size, void* d_ws, size_t ws_size,
                              hipStream_t stream) {
  (void)in_sizes; (void)n_in; (void)d_ws; (void)ws_size; (void)out_size;
  const float* x   = (const float*)d_in[0];
  const float* w0  = (const float*)d_in[1];
  const float* mu0 = (const float*)d_in[2];
  const float* sg0 = (const float*)d_in[3];
  float* out = (float*)d_out;

  prep_coef<<<1, 64, 0, stream>>>(w0, mu0, sg0);
  for (int it = 0; it < NITER; ++it) {
    em_mfma<<<NBLK, 256, 0, stream>>>(x);
    reduce_partials<<<dim3(54, 8), 64, 0, stream>>>();
    finalize_k<<<1, 64, 0, stream>>>();
  }
  const int nout = 64 + KDIM * LDIM + KDIM * LDIM * LDIM + 1;  // 44993
  writeout<<<(nout + 255) / 256, 256, 0, stream>>>(out);
}

// Round 2
// 579.597 us; speedup vs baseline: 1.1440x; 1.0485x over previous
//
#include <hip/hip_runtime.h>
#include <math.h>

typedef _Float16 f16x8 __attribute__((ext_vector_type(8)));
typedef float f32x16 __attribute__((ext_vector_type(16)));
typedef unsigned int uint4v __attribute__((ext_vector_type(4)));

namespace {
constexpr int LDIM = 26;
constexpr int KDIM = 64;
constexpr int NSAMP = 262144;
constexpr int NITER = 8;
constexpr float WFLOOR = 1e-5f;
constexpr float VFLOOR = 1e-6f;
constexpr float LOG2PI_TERM = 47.784803726642976f;  // 26 * ln(2*pi)
constexpr float L2E = 1.44269504088896340736f;
constexpr float LN2 = 0.69314718055994530942f;

constexpr int ACC_STRIDE = 53;                       // z, px[26], pxx[26]
constexpr int ACC_N = KDIM * ACC_STRIDE + 1;         // 3393 (last = ll)
constexpr int NCOPIES = 8;
constexpr int WROW = 36;                             // dwords per coef row
constexpr int NBLK = 1024;                           // 4 waves = 2 pairs; 256 samples/block
constexpr int PART_STRIDE = 3408;
}

// Static device storage (no dependence on the harness workspace; no device atomics).
__device__ float g_partial[NBLK * PART_STRIDE];                         // ~14 MB
__device__ float g_accum[NCOPIES * ACC_N];                              // 108 KB
__device__ float g_w[KDIM];
__device__ float g_mu[KDIM * LDIM];
__device__ float g_sig[KDIM * LDIM];
__device__ float g_ll[1];
__device__ __align__(16) unsigned g_coef[KDIM * WROW];                  // f16-pair coef rows

__device__ __forceinline__ unsigned pkrtz(float a, float b) {
  return __builtin_bit_cast(unsigned, __builtin_amdgcn_cvt_pkrtz(a, b));
}
__device__ __forceinline__ f16x8 ld8h(const unsigned* p) {
  uint4v v = *(const uint4v*)p;
  return __builtin_bit_cast(f16x8, v);
}
__device__ __forceinline__ f32x16 mfma16(f16x8 a, f16x8 b, f32x16 c) {
  return __builtin_amdgcn_mfma_f32_32x32x16_f16(a, b, c, 0, 0, 0);
}
// async global->LDS DMA, 16B per lane; LDS dest = wave-uniform base + lane*16
__device__ __forceinline__ void gload16(const void* g, void* l) {
  __builtin_amdgcn_global_load_lds(
      (const __attribute__((address_space(1))) unsigned*)g,
      (__attribute__((address_space(3))) unsigned*)l, 16, 0, 0);
}

// Coef row k (f16 pairs, 36-dword rows): slots 0..25 = -0.5/sig, 26..51 = mu/sig,
// 52 = C, 53 = C - f16(C) (split constant), rest 0.
__device__ void pack_row(int k, float w, const float* mu, const float* sg, unsigned* wp) {
  float A[LDIM], Bv[LDIM];
  float logdet = 0.f, q = 0.f;
#pragma unroll
  for (int l = 0; l < LDIM; ++l) {
    float pr = 1.0f / sg[l];
    logdet += __logf(sg[l]);
    A[l] = -0.5f * pr;
    Bv[l] = mu[l] * pr;
    q = __builtin_fmaf(mu[l] * mu[l], pr, q);
  }
  float C = __logf(w) - 0.5f * (LOG2PI_TERM + logdet + q);
  float Chi = (float)__builtin_amdgcn_cvt_pkrtz(C, 0.0f)[0];
  float Clo = C - Chi;
  unsigned* row = wp + k * WROW;
#define CF(f) ((f) < 26 ? A[(f)] : (f) < 52 ? Bv[(f) - 26] : (f) == 52 ? C : (f) == 53 ? Clo : 0.0f)
#pragma unroll
  for (int D = 0; D < 32; ++D) row[D] = pkrtz(CF(2 * D), CF(2 * D + 1));
#undef CF
#pragma unroll
  for (int D = 32; D < 36; ++D) row[D] = 0u;
}

__global__ void prep_coef(const float* __restrict__ w0, const float* __restrict__ mu0,
                          const float* __restrict__ sig0) {
  const int k = threadIdx.x;  // 64 threads
  float wv = w0[k];
  float s = wv;
#pragma unroll
  for (int d = 1; d < 64; d <<= 1) s += __shfl_xor(s, d, 64);
  float w = wv / s;
  float mu[LDIM], sg[LDIM];
#pragma unroll
  for (int l = 0; l < LDIM; ++l) {
    mu[l] = mu0[k * LDIM + l];
    sg[l] = sig0[k * LDIM + l];
  }
  pack_row(k, w, mu, sg, g_coef);
}

// k-split wave pairs: 4 waves/block = 2 pairs; within a pair, wave kh owns
// components [kh*32, kh*32+32). Sample rows are staged COALESCED via
// global_load_lds into a linear f32 double buffer (one tile ahead), then each
// lane reads its row from LDS. Softmax over all 64 k via single-barrier (m,s)
// pair exchange; the same barrier (preceded by vmcnt(0)) publishes the
// next tile's staged data.
__global__ __launch_bounds__(256, 4) void em_mfma(const float* __restrict__ x) {
  __shared__ __align__(16) unsigned char xtbuf[2][2][2][2048];  // [pair][buf][XT|SQT]
  __shared__ __align__(16) unsigned char ptbuf[4][2048];        // per-wave P^T (32x32 f16)
  __shared__ float2 exch[2][2][2][32];                          // [buf][pair][kh][sl] = (m,s)
  __shared__ __align__(16) float stage[2][2][32 * LDIM];        // [pair][buf] 32 rows x 26 f32

  const int tid = threadIdx.x;
  const int lane = tid & 63;
  const int warp = tid >> 6;
  const int pair = warp >> 1;
  const int kh = warp & 1;
  const int sl = lane & 31;
  const int h = lane >> 5;

  unsigned short* PTs = (unsigned short*)&ptbuf[warp][0];
  const unsigned* PTd = (const unsigned*)&ptbuf[warp][0];

  f32x16 aX = {0,0,0,0,0,0,0,0,0,0,0,0,0,0,0,0};
  f32x16 aQ = {0,0,0,0,0,0,0,0,0,0,0,0,0,0,0,0};
  float llacc = 0.f;

  const int sbase = blockIdx.x * 256 + pair * 128;
  const int rowbase = (kh * 32 + sl) * WROW;

  // ---- hoisted coefficient fragments (loop-invariant across tiles) ----
  f16x8 ca0 = ld8h(g_coef + rowbase + 0 + 4 * h);
  f16x8 ca1 = ld8h(g_coef + rowbase + 8 + 4 * h);
  f16x8 ca2 = ld8h(g_coef + rowbase + 16 + 4 * h);
  f16x8 ca3 = ld8h(g_coef + rowbase + 24 + 4 * h);

  // cooperative coalesced stage of tile tt: 32 rows x 104B = 3328B contiguous.
  // wave kh covers 16B-chunks [kh*104, kh*104+104): 64 lanes + 40 lanes.
  auto stage_tile = [&](int tt) {
    const uint4v* tb = (const uint4v*)(x + (size_t)(sbase + 32 * tt) * LDIM);
    char* db = (char*)&stage[pair][tt & 1][0] + kh * 1664;
    gload16(tb + kh * 104 + lane, db + (size_t)lane * 16);
    if (lane < 40)
      gload16(tb + kh * 104 + 64 + lane, db + 1024 + (size_t)lane * 16);
  };

  stage_tile(0);
  asm volatile("s_waitcnt vmcnt(0)" ::: "memory");
  __syncthreads();

#pragma unroll
  for (int t = 0; t < 4; ++t) {
    // ---- read own sample row from stage; pack to f16 pairs (x, x^2) ----
    unsigned xhu[13], squ[13];
    {
      const float2* srow = (const float2*)&stage[pair][t & 1][sl * LDIM];
#pragma unroll
      for (int j = 0; j < 13; ++j) {
        float2 v = srow[j];
        xhu[j] = pkrtz(v.x, v.y);
        squ[j] = pkrtz(v.x * v.x, v.y * v.y);
      }
    }
    // ---- issue next tile's coalesced loads (latency hidden under this tile) ----
    if (t < 3) stage_tile(t + 1);

    // ---- scatter transposes into pair-shared buffers (kh0: XT, kh1: SQT) ----
    unsigned short* XTs = (unsigned short*)&xtbuf[pair][t & 1][0][0];
    unsigned short* SQs = (unsigned short*)&xtbuf[pair][t & 1][1][0];
    {
      unsigned short* Ts = kh ? SQs : XTs;
#pragma unroll
      for (int c = 0; c < LDIM; ++c) {
        unsigned v = (c & 1) ? ((kh ? squ[c >> 1] : xhu[c >> 1]) >> 16)
                             : ((kh ? squ[c >> 1] : xhu[c >> 1]) & 0xffffu);
        Ts[(c * 32 + sl) ^ ((c & 7) << 3)] = (unsigned short)v;
      }
      Ts[(26 * 32 + sl) ^ ((26 & 7) << 3)] = kh ? (unsigned short)0 : (unsigned short)0x3C00;
    }

    // ---- E GEMM: e[k_local, s] for own k-half ----
    f32x16 e = {0,0,0,0,0,0,0,0,0,0,0,0,0,0,0,0};
    {
      uint4v b0 = {h ? squ[4] : squ[0], h ? squ[5] : squ[1],
                   h ? squ[6] : squ[2], h ? squ[7] : squ[3]};
      e = mfma16(ca0, __builtin_bit_cast(f16x8, b0), e);
      uint4v b1 = {h ? squ[12] : squ[8], h ? xhu[0] : squ[9],
                   h ? xhu[1] : squ[10], h ? xhu[2] : squ[11]};
      e = mfma16(ca1, __builtin_bit_cast(f16x8, b1), e);
      uint4v b2 = {h ? xhu[7] : xhu[3], h ? xhu[8] : xhu[4],
                   h ? xhu[9] : xhu[5], h ? xhu[10] : xhu[6]};
      e = mfma16(ca2, __builtin_bit_cast(f16x8, b2), e);
      uint4v b3 = {h ? 0u : xhu[11], h ? 0u : xhu[12],
                   h ? 0u : 0x3C003C00u, 0u};
      e = mfma16(ca3, __builtin_bit_cast(f16x8, b3), e);
    }

    // ---- softmax over all 64 k: in-lane tree + cross-half shfl + ONE-barrier
    //      (m,s) pair exchange; barrier also publishes next tile's stage ----
    float m8[8];
#pragma unroll
    for (int r = 0; r < 8; ++r) m8[r] = fmaxf(e[r], e[r + 8]);
#pragma unroll
    for (int d = 4; d > 0; d >>= 1)
#pragma unroll
      for (int r = 0; r < d; ++r) m8[r] = fmaxf(m8[r], m8[r + d]);
    float mh = fmaxf(m8[0], __shfl_xor(m8[0], 32));     // max over own 32 k
    const float mhL = mh * L2E;
#pragma unroll
    for (int r = 0; r < 16; ++r)
      e[r] = __builtin_amdgcn_exp2f(__builtin_fmaf(e[r], L2E, -mhL));
    float s8[8];
#pragma unroll
    for (int r = 0; r < 8; ++r) s8[r] = e[r] + e[r + 8];
#pragma unroll
    for (int d = 4; d > 0; d >>= 1)
#pragma unroll
      for (int r = 0; r < d; ++r) s8[r] += s8[r + d];
    float sh = s8[0] + __shfl_xor(s8[0], 32);           // sum exp(e - mh) over own 32 k
    exch[t & 1][pair][kh][sl] = make_float2(mh, sh);
    asm volatile("s_waitcnt vmcnt(0)" ::: "memory");    // drain next-tile stage DMA
    __syncthreads();
    float2 o = exch[t & 1][pair][kh ^ 1][sl];
    float M = fmaxf(mh, o.x);
    float eh = __builtin_amdgcn_exp2f((mh - M) * L2E);
    float eo = __builtin_amdgcn_exp2f((o.x - M) * L2E);
    float SS = __builtin_fmaf(sh, eh, o.y * eo);
    const float scale = eh * __builtin_amdgcn_rcpf(SS);
    if (kh == 0) llacc += M + __builtin_amdgcn_logf(SS) * LN2;  // counted by both lane-halves

    // ---- P^T scatter (own k-half rows; D-row mapping m74/m101) ----
#pragma unroll
    for (int r = 0; r < 16; ++r) {
      const int row = (r & 3) + 8 * (r >> 2) + 4 * h;
      _Float16 pv = (_Float16)(e[r] * scale);
      PTs[(row * 32 + sl) ^ ((row & 7) << 3)] = __builtin_bit_cast(unsigned short, pv);
    }

    // ---- M GEMM: aX += P.X^T (col26 -> z), aQ += P.SQ^T ----
    const unsigned* XTd = (const unsigned*)XTs;
    const unsigned* SQd = (const unsigned*)SQs;
#pragma unroll
    for (int ks = 0; ks < 2; ++ks) {
      const int off = 8 * ks + 4 * h;
      const int swz = (sl & 7) << 2;
      f16x8 a  = ld8h(&PTd[(sl * 16 + off) ^ swz]);
      f16x8 bx = ld8h(&XTd[(sl * 16 + off) ^ swz]);
      f16x8 bq = ld8h(&SQd[(sl * 16 + off) ^ swz]);
      aX = mfma16(a, bx, aX);
      aQ = mfma16(a, bq, aQ);
    }
  }

  // ---- epilogue: block reduce in LDS, then partial store (no global atomics) ----
  __syncthreads();
  float* red = (float*)&xtbuf[0][0][0][0];  // 3393 floats overlaying dead buffers
  for (int i = tid; i < ACC_N; i += 256) red[i] = 0.f;
  __syncthreads();
#pragma unroll
  for (int r = 0; r < 16; ++r) {
    const int row = kh * 32 + (r & 3) + 8 * (r >> 2) + 4 * h;
    const int n = sl;
    if (n < 26) {
      atomicAdd(&red[row * ACC_STRIDE + 1 + n], aX[r]);
      atomicAdd(&red[row * ACC_STRIDE + 27 + n], aQ[r]);
    } else if (n == 26) {
      atomicAdd(&red[row * ACC_STRIDE], aX[r]);
    }
  }
  float llw = llacc * 0.5f;  // each sample counted by both lane-halves of the kh0 wave
#pragma unroll
  for (int d = 1; d < 64; d <<= 1) llw += __shfl_xor(llw, d, 64);
  if (lane == 0 && kh == 0) atomicAdd(&red[KDIM * ACC_STRIDE], llw);
  __syncthreads();
  float* pb = g_partial + (size_t)blockIdx.x * PART_STRIDE;
  for (int i = tid; i < ACC_N; i += 256) pb[i] = red[i];
}

// fold 1024 block-partials into 8 accumulator copies (plain stores, no atomics)
__global__ void reduce_partials() {
  const int i = blockIdx.x * 256 + threadIdx.x;
  if (i >= ACC_N) return;
  const int cy = blockIdx.y;  // 8 chunks of 128 blocks
  const float* p = g_partial + (size_t)cy * 128 * PART_STRIDE + i;
  float s = 0.f;
#pragma unroll 8
  for (int j = 0; j < 128; ++j) s += p[(size_t)j * PART_STRIDE];
  g_accum[cy * ACC_N + i] = s;
}

__global__ void finalize_k() {
  const int k = threadIdx.x;  // 64 threads
  float vals[ACC_STRIDE];
#pragma unroll
  for (int j = 0; j < ACC_STRIDE; ++j) vals[j] = 0.f;
  float llsum = 0.f;
  for (int cp = 0; cp < NCOPIES; ++cp) {
    const float* a = g_accum + cp * ACC_N;
#pragma unroll
    for (int j = 0; j < ACC_STRIDE; ++j) vals[j] += a[k * ACC_STRIDE + j];
    llsum += a[KDIM * ACC_STRIDE];
  }
  float z = vals[0];
  float wn = z * (1.0f / NSAMP);
  float wf = fmaxf(wn, WFLOOR);
  float S = wf;
#pragma unroll
  for (int d = 1; d < 64; d <<= 1) S += __shfl_xor(S, d, 64);
  const float sf = WFLOOR * KDIM;
  float a = (1.0f - sf) / (S - sf);
  float b = WFLOOR * (1.0f - a);
  float w = a * wf + b;
  g_w[k] = w;
  float zinv = 1.0f / z;
  float muk[LDIM], sgk[LDIM];
#pragma unroll
  for (int l = 0; l < LDIM; ++l) {
    float m = vals[1 + l] * zinv;
    float s2 = fmaxf(__builtin_fmaf(-m, m, vals[27 + l] * zinv), VFLOOR);
    muk[l] = m;
    sgk[l] = s2;
    g_mu[k * LDIM + l] = m;
    g_sig[k * LDIM + l] = s2;
  }
  if (k == 0) g_ll[0] = llsum;
  pack_row(k, w, muk, sgk, g_coef);
}

__global__ void writeout(float* __restrict__ out) {
  const int i = blockIdx.x * 256 + threadIdx.x;
  // out: w[64] | mu[64*26] | sigma[64*26*26] (diag) | ll[1]
  if (i < 64) {
    out[i] = g_w[i];
  } else if (i < 64 + KDIM * LDIM) {
    out[i] = g_mu[i - 64];
  } else if (i < 64 + KDIM * LDIM + KDIM * LDIM * LDIM) {
    int t = i - (64 + KDIM * LDIM);
    int k = t / (LDIM * LDIM);
    int r = t % (LDIM * LDIM);
    int ii = r / LDIM;
    int jj = r % LDIM;
    out[i] = (ii == jj) ? g_sig[k * LDIM + ii] : 0.f;
  } else if (i == 64 + KDIM * LDIM + KDIM * LDIM * LDIM) {
    out[i] = g_ll[0];
  }
}

extern "C" void kernel_launch(void* const* d_in, const int* in_sizes, int n_in,
                              void* d_out, int out_size, void* d_ws, size_t ws_size,
                              hipStream_t stream) {
  (void)in_sizes; (void)n_in; (void)d_ws; (void)ws_size; (void)out_size;
  const float* x   = (const float*)d_in[0];
  const float* w0  = (const float*)d_in[1];
  const float* mu0 = (const float*)d_in[2];
  const float* sg0 = (const float*)d_in[3];
  float* out = (float*)d_out;

  prep_coef<<<1, 64, 0, stream>>>(w0, mu0, sg0);
  for (int it = 0; it < NITER; ++it) {
    em_mfma<<<NBLK, 256, 0, stream>>>(x);
    reduce_partials<<<dim3(14, 8), 256, 0, stream>>>();
    finalize_k<<<1, 64, 0, stream>>>();
  }
  const int nout = 64 + KDIM * LDIM + KDIM * LDIM * LDIM + 1;  // 44993
  writeout<<<(nout + 255) / 256, 256, 0, stream>>>(out);
}

// Round 3
// 365.178 us; speedup vs baseline: 1.8158x; 1.5872x over previous
//
#include <hip/hip_runtime.h>
#include <math.h>

typedef _Float16 f16x8 __attribute__((ext_vector_type(8)));
typedef float f32x16 __attribute__((ext_vector_type(16)));
typedef unsigned int uint4v __attribute__((ext_vector_type(4)));

namespace {
constexpr int LDIM = 26;
constexpr int KDIM = 64;
constexpr int NSAMP = 262144;
constexpr int NITER = 8;
constexpr float WFLOOR = 1e-5f;
constexpr float VFLOOR = 1e-6f;
constexpr float LOG2PI_TERM = 47.784803726642976f;  // 26 * ln(2*pi)
constexpr float L2E = 1.44269504088896340736f;
constexpr float LN2 = 0.69314718055994530942f;

constexpr int ACC_STRIDE = 53;                       // z, px[26], pxx[26]
constexpr int ACC_N = KDIM * ACC_STRIDE + 1;         // 3393 (last = ll)
constexpr int NCOPIES = 8;
constexpr int WROW = 36;                             // dwords per coef row
constexpr int NBLK = 2048;                           // 1 pair (2 waves) per block; 128 samples
constexpr int PART_STRIDE = 3408;
}

// Static device storage (no dependence on the harness workspace; no device atomics).
__device__ float g_partial[NBLK * PART_STRIDE];                         // ~28 MB
__device__ float g_accum[NCOPIES * ACC_N];                              // 108 KB
__device__ float g_w[KDIM];
__device__ float g_mu[KDIM * LDIM];
__device__ float g_sig[KDIM * LDIM];
__device__ float g_ll[1];
__device__ __align__(16) unsigned g_coef[KDIM * WROW];                  // f16-pair coef rows

__device__ __forceinline__ unsigned pkrtz(float a, float b) {
  return __builtin_bit_cast(unsigned, __builtin_amdgcn_cvt_pkrtz(a, b));
}
__device__ __forceinline__ f16x8 ld8h(const unsigned* p) {
  uint4v v = *(const uint4v*)p;
  return __builtin_bit_cast(f16x8, v);
}
__device__ __forceinline__ f32x16 mfma16(f16x8 a, f16x8 b, f32x16 c) {
  return __builtin_amdgcn_mfma_f32_32x32x16_f16(a, b, c, 0, 0, 0);
}
// async global->LDS DMA, 16B per lane
__device__ __forceinline__ void gload16(const void* g, void* l) {
  __builtin_amdgcn_global_load_lds(
      (const __attribute__((address_space(1))) unsigned*)g,
      (__attribute__((address_space(3))) unsigned*)l, 16, 0, 0);
}

// Coef row k (f16 pairs, 36-dword rows): slots 0..25 = -0.5/sig, 26..51 = mu/sig,
// 52 = C, 53 = C - f16(C) (split constant), rest 0.
__device__ void pack_row(int k, float w, const float* mu, const float* sg, unsigned* wp) {
  float A[LDIM], Bv[LDIM];
  float logdet = 0.f, q = 0.f;
#pragma unroll
  for (int l = 0; l < LDIM; ++l) {
    float pr = 1.0f / sg[l];
    logdet += __logf(sg[l]);
    A[l] = -0.5f * pr;
    Bv[l] = mu[l] * pr;
    q = __builtin_fmaf(mu[l] * mu[l], pr, q);
  }
  float C = __logf(w) - 0.5f * (LOG2PI_TERM + logdet + q);
  float Chi = (float)__builtin_amdgcn_cvt_pkrtz(C, 0.0f)[0];
  float Clo = C - Chi;
  unsigned* row = wp + k * WROW;
#define CF(f) ((f) < 26 ? A[(f)] : (f) < 52 ? Bv[(f) - 26] : (f) == 52 ? C : (f) == 53 ? Clo : 0.0f)
#pragma unroll
  for (int D = 0; D < 32; ++D) row[D] = pkrtz(CF(2 * D), CF(2 * D + 1));
#undef CF
#pragma unroll
  for (int D = 32; D < 36; ++D) row[D] = 0u;
}

__global__ void prep_coef(const float* __restrict__ w0, const float* __restrict__ mu0,
                          const float* __restrict__ sig0) {
  const int k = threadIdx.x;  // 64 threads
  float wv = w0[k];
  float s = wv;
#pragma unroll
  for (int d = 1; d < 64; d <<= 1) s += __shfl_xor(s, d, 64);
  float w = wv / s;
  float mu[LDIM], sg[LDIM];
#pragma unroll
  for (int l = 0; l < LDIM; ++l) {
    mu[l] = mu0[k * LDIM + l];
    sg[l] = sig0[k * LDIM + l];
  }
  pack_row(k, w, mu, sg, g_coef);
}

// One PAIR per workgroup (2 waves, 128 threads): wave kh owns components
// [kh*32, kh*32+32). All cross-wave sharing is pair-local, so the per-tile
// __syncthreads spans only 2 waves -> 8 independent barrier domains per CU.
// Each thread owns its (row,col) accumulator fragments exclusively within the
// pair, so the epilogue is a direct register->global partial store (no LDS
// reduce, no atomics).
__global__ __launch_bounds__(128, 4) void em_mfma(const float* __restrict__ x) {
  __shared__ __align__(16) unsigned char xtbuf[2][2][2048];   // [buf][XT|SQT]
  __shared__ __align__(16) unsigned char ptbuf[2][2048];      // per-wave P^T (32x32 f16)
  __shared__ float2 exch[2][2][32];                           // [buf][kh][sl] = (m,s)
  __shared__ __align__(16) float stage[2][32 * LDIM];         // [buf] 32 rows x 26 f32

  const int tid = threadIdx.x;
  const int lane = tid & 63;
  const int kh = tid >> 6;
  const int sl = lane & 31;
  const int h = lane >> 5;

  unsigned short* PTs = (unsigned short*)&ptbuf[kh][0];
  const unsigned* PTd = (const unsigned*)&ptbuf[kh][0];

  f32x16 aX = {0,0,0,0,0,0,0,0,0,0,0,0,0,0,0,0};
  f32x16 aQ = {0,0,0,0,0,0,0,0,0,0,0,0,0,0,0,0};
  float llacc = 0.f;

  const int sbase = blockIdx.x * 128;
  const int rowbase = (kh * 32 + sl) * WROW;

  // ---- hoisted coefficient fragments (loop-invariant across tiles) ----
  f16x8 ca0 = ld8h(g_coef + rowbase + 0 + 4 * h);
  f16x8 ca1 = ld8h(g_coef + rowbase + 8 + 4 * h);
  f16x8 ca2 = ld8h(g_coef + rowbase + 16 + 4 * h);
  f16x8 ca3 = ld8h(g_coef + rowbase + 24 + 4 * h);

  // cooperative coalesced stage of tile tt: 32 rows x 104B = 3328B contiguous;
  // wave kh covers 16B-chunks [kh*104, kh*104+104): 64 lanes + 40 lanes.
  auto stage_tile = [&](int tt) {
    const uint4v* tb = (const uint4v*)(x + (size_t)(sbase + 32 * tt) * LDIM);
    char* db = (char*)&stage[tt & 1][0] + kh * 1664;
    gload16(tb + kh * 104 + lane, db + (size_t)lane * 16);
    if (lane < 40)
      gload16(tb + kh * 104 + 64 + lane, db + 1024 + (size_t)lane * 16);
  };

  stage_tile(0);
  asm volatile("s_waitcnt vmcnt(0)" ::: "memory");
  __syncthreads();

#pragma unroll
  for (int t = 0; t < 4; ++t) {
    // ---- issue next tile's DMA first (max latency cover; overwritten buffer
    //      was last read before barrier t-1, so both waves are done with it) ----
    if (t < 3) stage_tile(t + 1);

    // ---- read own sample row from stage; pack to f16 pairs (x, x^2) ----
    unsigned xhu[13], squ[13];
    {
      const float2* srow = (const float2*)&stage[t & 1][sl * LDIM];
#pragma unroll
      for (int j = 0; j < 13; ++j) {
        float2 v = srow[j];
        xhu[j] = pkrtz(v.x, v.y);
        squ[j] = pkrtz(v.x * v.x, v.y * v.y);
      }
    }

    // ---- scatter transposes into pair-shared buffers (kh0: XT, kh1: SQT) ----
    unsigned short* XTs = (unsigned short*)&xtbuf[t & 1][0][0];
    unsigned short* SQs = (unsigned short*)&xtbuf[t & 1][1][0];
    {
      unsigned short* Ts = kh ? SQs : XTs;
#pragma unroll
      for (int c = 0; c < LDIM; ++c) {
        unsigned v = (c & 1) ? ((kh ? squ[c >> 1] : xhu[c >> 1]) >> 16)
                             : ((kh ? squ[c >> 1] : xhu[c >> 1]) & 0xffffu);
        Ts[(c * 32 + sl) ^ ((c & 7) << 3)] = (unsigned short)v;
      }
      Ts[(26 * 32 + sl) ^ ((26 & 7) << 3)] = kh ? (unsigned short)0 : (unsigned short)0x3C00;
    }

    // ---- E GEMM: e[k_local, s] for own k-half ----
    f32x16 e = {0,0,0,0,0,0,0,0,0,0,0,0,0,0,0,0};
    {
      uint4v b0 = {h ? squ[4] : squ[0], h ? squ[5] : squ[1],
                   h ? squ[6] : squ[2], h ? squ[7] : squ[3]};
      e = mfma16(ca0, __builtin_bit_cast(f16x8, b0), e);
      uint4v b1 = {h ? squ[12] : squ[8], h ? xhu[0] : squ[9],
                   h ? xhu[1] : squ[10], h ? xhu[2] : squ[11]};
      e = mfma16(ca1, __builtin_bit_cast(f16x8, b1), e);
      uint4v b2 = {h ? xhu[7] : xhu[3], h ? xhu[8] : xhu[4],
                   h ? xhu[9] : xhu[5], h ? xhu[10] : xhu[6]};
      e = mfma16(ca2, __builtin_bit_cast(f16x8, b2), e);
      uint4v b3 = {h ? 0u : xhu[11], h ? 0u : xhu[12],
                   h ? 0u : 0x3C003C00u, 0u};
      e = mfma16(ca3, __builtin_bit_cast(f16x8, b3), e);
    }

    // ---- softmax over all 64 k: in-lane tree + cross-half shfl + ONE pair
    //      barrier: (m,s) exchange; barrier also publishes next tile's stage ----
    float m8[8];
#pragma unroll
    for (int r = 0; r < 8; ++r) m8[r] = fmaxf(e[r], e[r + 8]);
#pragma unroll
    for (int d = 4; d > 0; d >>= 1)
#pragma unroll
      for (int r = 0; r < d; ++r) m8[r] = fmaxf(m8[r], m8[r + d]);
    float mh = fmaxf(m8[0], __shfl_xor(m8[0], 32));     // max over own 32 k
    const float mhL = mh * L2E;
#pragma unroll
    for (int r = 0; r < 16; ++r)
      e[r] = __builtin_amdgcn_exp2f(__builtin_fmaf(e[r], L2E, -mhL));
    float s8[8];
#pragma unroll
    for (int r = 0; r < 8; ++r) s8[r] = e[r] + e[r + 8];
#pragma unroll
    for (int d = 4; d > 0; d >>= 1)
#pragma unroll
      for (int r = 0; r < d; ++r) s8[r] += s8[r + d];
    float sh = s8[0] + __shfl_xor(s8[0], 32);           // sum exp(e - mh) over own 32 k
    exch[t & 1][kh][sl] = make_float2(mh, sh);
    asm volatile("s_waitcnt vmcnt(0)" ::: "memory");    // drain next-tile stage DMA
    __syncthreads();
    float2 o = exch[t & 1][kh ^ 1][sl];
    float M = fmaxf(mh, o.x);
    float eh = __builtin_amdgcn_exp2f((mh - M) * L2E);
    float eo = __builtin_amdgcn_exp2f((o.x - M) * L2E);
    float SS = __builtin_fmaf(sh, eh, o.y * eo);
    const float scale = eh * __builtin_amdgcn_rcpf(SS);
    if (kh == 0) llacc += M + __builtin_amdgcn_logf(SS) * LN2;  // counted by both lane-halves

    // ---- P^T scatter (own k-half rows; D-row mapping m74/m101) ----
#pragma unroll
    for (int r = 0; r < 16; ++r) {
      const int row = (r & 3) + 8 * (r >> 2) + 4 * h;
      _Float16 pv = (_Float16)(e[r] * scale);
      PTs[(row * 32 + sl) ^ ((row & 7) << 3)] = __builtin_bit_cast(unsigned short, pv);
    }

    // ---- M GEMM: aX += P.X^T (col26 -> z), aQ += P.SQ^T ----
    const unsigned* XTd = (const unsigned*)XTs;
    const unsigned* SQd = (const unsigned*)SQs;
#pragma unroll
    for (int ks = 0; ks < 2; ++ks) {
      const int off = 8 * ks + 4 * h;
      const int swz = (sl & 7) << 2;
      f16x8 a  = ld8h(&PTd[(sl * 16 + off) ^ swz]);
      f16x8 bx = ld8h(&XTd[(sl * 16 + off) ^ swz]);
      f16x8 bq = ld8h(&SQd[(sl * 16 + off) ^ swz]);
      aX = mfma16(a, bx, aX);
      aQ = mfma16(a, bq, aQ);
    }
  }

  // ---- epilogue: each (row,col) owned by exactly one thread in the pair ->
  //      direct register->global partial store. No LDS reduce, no atomics. ----
  float* pb = g_partial + (size_t)blockIdx.x * PART_STRIDE;
#pragma unroll
  for (int r = 0; r < 16; ++r) {
    const int row = kh * 32 + (r & 3) + 8 * (r >> 2) + 4 * h;
    if (sl < 26) {
      pb[row * ACC_STRIDE + 1 + sl] = aX[r];
      pb[row * ACC_STRIDE + 27 + sl] = aQ[r];
    } else if (sl == 26) {
      pb[row * ACC_STRIDE] = aX[r];
    }
  }
  float llw = llacc * 0.5f;  // each sample counted by both lane-halves of the kh0 wave
#pragma unroll
  for (int d = 1; d < 64; d <<= 1) llw += __shfl_xor(llw, d, 64);
  if (kh == 0 && lane == 0) pb[KDIM * ACC_STRIDE] = llw;
}

// fold 2048 block-partials into 8 accumulator copies (plain stores, no atomics)
__global__ void reduce_partials() {
  const int i = blockIdx.x * 256 + threadIdx.x;
  if (i >= ACC_N) return;
  const int cy = blockIdx.y;  // 8 chunks of 256 blocks
  const float* p = g_partial + (size_t)cy * 256 * PART_STRIDE + i;
  float s = 0.f;
#pragma unroll 8
  for (int j = 0; j < 256; ++j) s += p[(size_t)j * PART_STRIDE];
  g_accum[cy * ACC_N + i] = s;
}

__global__ void finalize_k() {
  const int k = threadIdx.x;  // 64 threads
  float vals[ACC_STRIDE];
#pragma unroll
  for (int j = 0; j < ACC_STRIDE; ++j) vals[j] = 0.f;
  float llsum = 0.f;
  for (int cp = 0; cp < NCOPIES; ++cp) {
    const float* a = g_accum + cp * ACC_N;
#pragma unroll
    for (int j = 0; j < ACC_STRIDE; ++j) vals[j] += a[k * ACC_STRIDE + j];
    llsum += a[KDIM * ACC_STRIDE];
  }
  float z = vals[0];
  float wn = z * (1.0f / NSAMP);
  float wf = fmaxf(wn, WFLOOR);
  float S = wf;
#pragma unroll
  for (int d = 1; d < 64; d <<= 1) S += __shfl_xor(S, d, 64);
  const float sf = WFLOOR * KDIM;
  float a = (1.0f - sf) / (S - sf);
  float b = WFLOOR * (1.0f - a);
  float w = a * wf + b;
  g_w[k] = w;
  float zinv = 1.0f / z;
  float muk[LDIM], sgk[LDIM];
#pragma unroll
  for (int l = 0; l < LDIM; ++l) {
    float m = vals[1 + l] * zinv;
    float s2 = fmaxf(__builtin_fmaf(-m, m, vals[27 + l] * zinv), VFLOOR);
    muk[l] = m;
    sgk[l] = s2;
    g_mu[k * LDIM + l] = m;
    g_sig[k * LDIM + l] = s2;
  }
  if (k == 0) g_ll[0] = llsum;
  pack_row(k, w, muk, sgk, g_coef);
}

__global__ void writeout(const float* __restrict__ dummy, float* __restrict__ out) {
  const int i = blockIdx.x * 256 + threadIdx.x;
  // out: w[64] | mu[64*26] | sigma[64*26*26] (diag) | ll[1]
  if (i < 64) {
    out[i] = g_w[i];
  } else if (i < 64 + KDIM * LDIM) {
    out[i] = g_mu[i - 64];
  } else if (i < 64 + KDIM * LDIM + KDIM * LDIM * LDIM) {
    int t = i - (64 + KDIM * LDIM);
    int k = t / (LDIM * LDIM);
    int r = t % (LDIM * LDIM);
    int ii = r / LDIM;
    int jj = r % LDIM;
    out[i] = (ii == jj) ? g_sig[k * LDIM + ii] : 0.f;
  } else if (i == 64 + KDIM * LDIM + KDIM * LDIM * LDIM) {
    out[i] = g_ll[0];
  }
}

extern "C" void kernel_launch(void* const* d_in, const int* in_sizes, int n_in,
                              void* d_out, int out_size, void* d_ws, size_t ws_size,
                              hipStream_t stream) {
  (void)in_sizes; (void)n_in; (void)d_ws; (void)ws_size; (void)out_size;
  const float* x   = (const float*)d_in[0];
  const float* w0  = (const float*)d_in[1];
  const float* mu0 = (const float*)d_in[2];
  const float* sg0 = (const float*)d_in[3];
  float* out = (float*)d_out;

  prep_coef<<<1, 64, 0, stream>>>(w0, mu0, sg0);
  for (int it = 0; it < NITER; ++it) {
    em_mfma<<<NBLK, 128, 0, stream>>>(x);
    reduce_partials<<<dim3(14, 8), 256, 0, stream>>>();
    finalize_k<<<1, 64, 0, stream>>>();
  }
  const int nout = 64 + KDIM * LDIM + KDIM * LDIM * LDIM + 1;  // 44993
  writeout<<<(nout + 255) / 256, 256, 0, stream>>>(x, out);
}

// Round 4
// 348.619 us; speedup vs baseline: 1.9020x; 1.0475x over previous
//
#include <hip/hip_runtime.h>
#include <math.h>

typedef _Float16 f16x8 __attribute__((ext_vector_type(8)));
typedef float f32x16 __attribute__((ext_vector_type(16)));
typedef unsigned int uint4v __attribute__((ext_vector_type(4)));

namespace {
constexpr int LDIM = 26;
constexpr int KDIM = 64;
constexpr int NSAMP = 262144;
constexpr int NITER = 8;
constexpr float WFLOOR = 1e-5f;
constexpr float VFLOOR = 1e-6f;
constexpr float LOG2PI_TERM = 47.784803726642976f;  // 26 * ln(2*pi)
constexpr float L2E = 1.44269504088896340736f;
constexpr float LN2 = 0.69314718055994530942f;

constexpr int ACC_STRIDE = 53;                       // z, px[26], pxx[26]
constexpr int ACC_N = KDIM * ACC_STRIDE + 1;         // 3393 (last = ll)
constexpr int NCOPIES = 8;
constexpr int WROW = 36;                             // dwords per coef row
constexpr int NBLK = 2048;                           // 1 wave per block; 128 samples each
constexpr int PART_STRIDE = 3408;
}

// Static device storage (no dependence on the harness workspace; no device atomics).
__device__ float g_partial[NBLK * PART_STRIDE];                         // ~28 MB
__device__ float g_accum[NCOPIES * ACC_N];                              // 108 KB
__device__ float g_w[KDIM];
__device__ float g_mu[KDIM * LDIM];
__device__ float g_sig[KDIM * LDIM];
__device__ float g_ll[1];
__device__ __align__(16) unsigned g_coef[KDIM * WROW];                  // f16-pair coef rows

__device__ __forceinline__ unsigned pkrtz(float a, float b) {
  return __builtin_bit_cast(unsigned, __builtin_amdgcn_cvt_pkrtz(a, b));
}
__device__ __forceinline__ f16x8 ld8h(const unsigned* p) {
  uint4v v = *(const uint4v*)p;
  return __builtin_bit_cast(f16x8, v);
}
__device__ __forceinline__ f32x16 mfma16(f16x8 a, f16x8 b, f32x16 c) {
  return __builtin_amdgcn_mfma_f32_32x32x16_f16(a, b, c, 0, 0, 0);
}
// async global->LDS DMA, 16B per lane
__device__ __forceinline__ void gload16(const void* g, void* l) {
  __builtin_amdgcn_global_load_lds(
      (const __attribute__((address_space(1))) unsigned*)g,
      (__attribute__((address_space(3))) unsigned*)l, 16, 0, 0);
}

// Coef row k (f16 pairs, 36-dword rows): slots 0..25 = -0.5/sig, 26..51 = mu/sig,
// 52 = C, 53 = C - f16(C) (split constant), rest 0.
__device__ void pack_row(int k, float w, const float* mu, const float* sg, unsigned* wp) {
  float A[LDIM], Bv[LDIM];
  float logdet = 0.f, q = 0.f;
#pragma unroll
  for (int l = 0; l < LDIM; ++l) {
    float pr = 1.0f / sg[l];
    logdet += __logf(sg[l]);
    A[l] = -0.5f * pr;
    Bv[l] = mu[l] * pr;
    q = __builtin_fmaf(mu[l] * mu[l], pr, q);
  }
  float C = __logf(w) - 0.5f * (LOG2PI_TERM + logdet + q);
  float Chi = (float)__builtin_amdgcn_cvt_pkrtz(C, 0.0f)[0];
  float Clo = C - Chi;
  unsigned* row = wp + k * WROW;
#define CF(f) ((f) < 26 ? A[(f)] : (f) < 52 ? Bv[(f) - 26] : (f) == 52 ? C : (f) == 53 ? Clo : 0.0f)
#pragma unroll
  for (int D = 0; D < 32; ++D) row[D] = pkrtz(CF(2 * D), CF(2 * D + 1));
#undef CF
#pragma unroll
  for (int D = 32; D < 36; ++D) row[D] = 0u;
}

__global__ void prep_coef(const float* __restrict__ w0, const float* __restrict__ mu0,
                          const float* __restrict__ sig0) {
  const int k = threadIdx.x;  // 64 threads
  float wv = w0[k];
  float s = wv;
#pragma unroll
  for (int d = 1; d < 64; d <<= 1) s += __shfl_xor(s, d, 64);
  float w = wv / s;
  float mu[LDIM], sg[LDIM];
#pragma unroll
  for (int l = 0; l < LDIM; ++l) {
    mu[l] = mu0[k * LDIM + l];
    sg[l] = sig0[k * LDIM + l];
  }
  pack_row(k, w, mu, sg, g_coef);
}

// ONE WAVE per workgroup (64 threads), 128 samples (4 tiles of 32). The wave
// holds BOTH k-halves (2x coef frags, 4 accumulators), so the softmax over all
// 64 components is in-lane tree + one shfl_xor(32): ZERO __syncthreads in the
// whole kernel. Pure per-wave dataflow; only vmcnt/lgkmcnt waits remain.
// Each (row,col) accumulator element is owned by exactly one lane -> direct
// register->global partial store.
__global__ __launch_bounds__(64, 2) void em_mfma(const float* __restrict__ x) {
  __shared__ __align__(16) unsigned char xtbuf[2][2048];      // XT | SQT (single-buffered)
  __shared__ __align__(16) unsigned char ptbuf[2][2048];      // PT half0 | half1
  __shared__ __align__(16) float stage[2][32 * LDIM];         // [buf] 32 rows x 26 f32

  const int lane = threadIdx.x & 63;
  const int sl = lane & 31;
  const int h = lane >> 5;

  unsigned short* PT0s = (unsigned short*)&ptbuf[0][0];
  unsigned short* PT1s = (unsigned short*)&ptbuf[1][0];
  const unsigned* PT0d = (const unsigned*)&ptbuf[0][0];
  const unsigned* PT1d = (const unsigned*)&ptbuf[1][0];

  f32x16 aX0 = {0,0,0,0,0,0,0,0,0,0,0,0,0,0,0,0};
  f32x16 aX1 = {0,0,0,0,0,0,0,0,0,0,0,0,0,0,0,0};
  f32x16 aQ0 = {0,0,0,0,0,0,0,0,0,0,0,0,0,0,0,0};
  f32x16 aQ1 = {0,0,0,0,0,0,0,0,0,0,0,0,0,0,0,0};
  float llacc = 0.f;

  const int sbase = blockIdx.x * 128;
  const int rowbase0 = sl * WROW;
  const int rowbase1 = (32 + sl) * WROW;

  // ---- hoisted coefficient fragments for BOTH k-halves ----
  f16x8 ca00 = ld8h(g_coef + rowbase0 + 0 + 4 * h);
  f16x8 ca01 = ld8h(g_coef + rowbase0 + 8 + 4 * h);
  f16x8 ca02 = ld8h(g_coef + rowbase0 + 16 + 4 * h);
  f16x8 ca03 = ld8h(g_coef + rowbase0 + 24 + 4 * h);
  f16x8 ca10 = ld8h(g_coef + rowbase1 + 0 + 4 * h);
  f16x8 ca11 = ld8h(g_coef + rowbase1 + 8 + 4 * h);
  f16x8 ca12 = ld8h(g_coef + rowbase1 + 16 + 4 * h);
  f16x8 ca13 = ld8h(g_coef + rowbase1 + 24 + 4 * h);

  // coalesced stage of tile tt: 32 rows x 104B = 3328B = 208 16B-chunks.
  auto stage_tile = [&](int tt) {
    const uint4v* tb = (const uint4v*)(x + (size_t)(sbase + 32 * tt) * LDIM);
    char* db = (char*)&stage[tt & 1][0];
    gload16(tb + lane, db + (size_t)lane * 16);
    gload16(tb + 64 + lane, db + 1024 + (size_t)lane * 16);
    gload16(tb + 128 + lane, db + 2048 + (size_t)lane * 16);
    if (lane < 16) gload16(tb + 192 + lane, db + 3072 + (size_t)lane * 16);
  };

  stage_tile(0);

#pragma unroll
  for (int t = 0; t < 4; ++t) {
    // drain this tile's DMA (issued a full tile ago, except t=0)
    asm volatile("s_waitcnt vmcnt(0)" ::: "memory");

    // ---- read own sample row from stage; pack to f16 pairs (x, x^2) ----
    unsigned xhu[13], squ[13];
    {
      const float2* srow = (const float2*)&stage[t & 1][sl * LDIM];
#pragma unroll
      for (int j = 0; j < 13; ++j) {
        float2 v = srow[j];
        xhu[j] = pkrtz(v.x, v.y);
        squ[j] = pkrtz(v.x * v.x, v.y * v.y);
      }
    }

    // ---- issue next tile's DMA (consumed at top of t+1: full-tile cover) ----
    if (t < 3) stage_tile(t + 1);

    // ---- scatter transposes (XT and SQT, lanes h==0 only; single-buffered:
    //      M-GEMM(t-1) reads precede these writes in this wave's program order) ----
    unsigned short* XTs = (unsigned short*)&xtbuf[0][0];
    unsigned short* SQs = (unsigned short*)&xtbuf[1][0];
    if (h == 0) {
#pragma unroll
      for (int c = 0; c < LDIM; ++c) {
        unsigned xvv = (c & 1) ? (xhu[c >> 1] >> 16) : (xhu[c >> 1] & 0xffffu);
        unsigned svv = (c & 1) ? (squ[c >> 1] >> 16) : (squ[c >> 1] & 0xffffu);
        const int idx = (c * 32 + sl) ^ ((c & 7) << 3);
        XTs[idx] = (unsigned short)xvv;
        SQs[idx] = (unsigned short)svv;
      }
      const int idx26 = (26 * 32 + sl) ^ ((26 & 7) << 3);
      XTs[idx26] = (unsigned short)0x3C00;
      SQs[idx26] = (unsigned short)0;
    }

    // ---- E GEMM: e0 (k 0..31), e1 (k 32..63); shared B fragments ----
    f32x16 e0 = {0,0,0,0,0,0,0,0,0,0,0,0,0,0,0,0};
    f32x16 e1 = {0,0,0,0,0,0,0,0,0,0,0,0,0,0,0,0};
    {
      uint4v b0 = {h ? squ[4] : squ[0], h ? squ[5] : squ[1],
                   h ? squ[6] : squ[2], h ? squ[7] : squ[3]};
      uint4v b1 = {h ? squ[12] : squ[8], h ? xhu[0] : squ[9],
                   h ? xhu[1] : squ[10], h ? xhu[2] : squ[11]};
      uint4v b2 = {h ? xhu[7] : xhu[3], h ? xhu[8] : xhu[4],
                   h ? xhu[9] : xhu[5], h ? xhu[10] : xhu[6]};
      uint4v b3 = {h ? 0u : xhu[11], h ? 0u : xhu[12],
                   h ? 0u : 0x3C003C00u, 0u};
      f16x8 fb0 = __builtin_bit_cast(f16x8, b0);
      f16x8 fb1 = __builtin_bit_cast(f16x8, b1);
      f16x8 fb2 = __builtin_bit_cast(f16x8, b2);
      f16x8 fb3 = __builtin_bit_cast(f16x8, b3);
      e0 = mfma16(ca00, fb0, e0);
      e1 = mfma16(ca10, fb0, e1);
      e0 = mfma16(ca01, fb1, e0);
      e1 = mfma16(ca11, fb1, e1);
      e0 = mfma16(ca02, fb2, e0);
      e1 = mfma16(ca12, fb2, e1);
      e0 = mfma16(ca03, fb3, e0);
      e1 = mfma16(ca13, fb3, e1);
    }

    // ---- softmax over all 64 k: in-lane tree over 32 regs + shfl_xor(32) ----
    float m8[8];
#pragma unroll
    for (int r = 0; r < 8; ++r)
      m8[r] = fmaxf(fmaxf(e0[r], e0[r + 8]), fmaxf(e1[r], e1[r + 8]));
#pragma unroll
    for (int d = 4; d > 0; d >>= 1)
#pragma unroll
      for (int r = 0; r < d; ++r) m8[r] = fmaxf(m8[r], m8[r + d]);
    const float M = fmaxf(m8[0], __shfl_xor(m8[0], 32));  // max over all 64 k
    const float mL = M * L2E;
#pragma unroll
    for (int r = 0; r < 16; ++r) {
      e0[r] = __builtin_amdgcn_exp2f(__builtin_fmaf(e0[r], L2E, -mL));
      e1[r] = __builtin_amdgcn_exp2f(__builtin_fmaf(e1[r], L2E, -mL));
    }
    float s8[8];
#pragma unroll
    for (int r = 0; r < 8; ++r)
      s8[r] = (e0[r] + e0[r + 8]) + (e1[r] + e1[r + 8]);
#pragma unroll
    for (int d = 4; d > 0; d >>= 1)
#pragma unroll
      for (int r = 0; r < d; ++r) s8[r] += s8[r + d];
    const float SS = s8[0] + __shfl_xor(s8[0], 32);       // sum over all 64 k
    const float scale = __builtin_amdgcn_rcpf(SS);
    llacc += M + __builtin_amdgcn_logf(SS) * LN2;         // counted by both lane-halves

    // ---- P^T scatter, both halves (D-row mapping m74/m101) ----
#pragma unroll
    for (int r = 0; r < 16; ++r) {
      const int row = (r & 3) + 8 * (r >> 2) + 4 * h;
      const int idx = (row * 32 + sl) ^ ((row & 7) << 3);
      _Float16 p0 = (_Float16)(e0[r] * scale);
      _Float16 p1 = (_Float16)(e1[r] * scale);
      PT0s[idx] = __builtin_bit_cast(unsigned short, p0);
      PT1s[idx] = __builtin_bit_cast(unsigned short, p1);
    }

    // ---- M GEMM: aX += P.X^T (col26 -> z), aQ += P.SQ^T, both halves ----
    const unsigned* XTd = (const unsigned*)XTs;
    const unsigned* SQd = (const unsigned*)SQs;
#pragma unroll
    for (int ks = 0; ks < 2; ++ks) {
      const int off = 8 * ks + 4 * h;
      const int swz = (sl & 7) << 2;
      f16x8 a0 = ld8h(&PT0d[(sl * 16 + off) ^ swz]);
      f16x8 a1 = ld8h(&PT1d[(sl * 16 + off) ^ swz]);
      f16x8 bx = ld8h(&XTd[(sl * 16 + off) ^ swz]);
      f16x8 bq = ld8h(&SQd[(sl * 16 + off) ^ swz]);
      aX0 = mfma16(a0, bx, aX0);
      aQ0 = mfma16(a0, bq, aQ0);
      aX1 = mfma16(a1, bx, aX1);
      aQ1 = mfma16(a1, bq, aQ1);
    }
  }

  // ---- epilogue: direct register->global partial store (no LDS, no atomics) ----
  float* pb = g_partial + (size_t)blockIdx.x * PART_STRIDE;
#pragma unroll
  for (int r = 0; r < 16; ++r) {
    const int row = (r & 3) + 8 * (r >> 2) + 4 * h;
    if (sl < 26) {
      pb[row * ACC_STRIDE + 1 + sl] = aX0[r];
      pb[row * ACC_STRIDE + 27 + sl] = aQ0[r];
      pb[(row + 32) * ACC_STRIDE + 1 + sl] = aX1[r];
      pb[(row + 32) * ACC_STRIDE + 27 + sl] = aQ1[r];
    } else if (sl == 26) {
      pb[row * ACC_STRIDE] = aX0[r];
      pb[(row + 32) * ACC_STRIDE] = aX1[r];
    }
  }
  float llw = llacc * 0.5f;  // each sample counted by both lane-halves
#pragma unroll
  for (int d = 1; d < 64; d <<= 1) llw += __shfl_xor(llw, d, 64);
  if (lane == 0) pb[KDIM * ACC_STRIDE] = llw;
}

// fold 2048 block-partials into 8 accumulator copies (plain stores, no atomics)
__global__ void reduce_partials() {
  const int i = blockIdx.x * 256 + threadIdx.x;
  if (i >= ACC_N) return;
  const int cy = blockIdx.y;  // 8 chunks of 256 blocks
  const float* p = g_partial + (size_t)cy * 256 * PART_STRIDE + i;
  float s = 0.f;
#pragma unroll 8
  for (int j = 0; j < 256; ++j) s += p[(size_t)j * PART_STRIDE];
  g_accum[cy * ACC_N + i] = s;
}

__global__ void finalize_k() {
  const int k = threadIdx.x;  // 64 threads
  float vals[ACC_STRIDE];
#pragma unroll
  for (int j = 0; j < ACC_STRIDE; ++j) vals[j] = 0.f;
  float llsum = 0.f;
  for (int cp = 0; cp < NCOPIES; ++cp) {
    const float* a = g_accum + cp * ACC_N;
#pragma unroll
    for (int j = 0; j < ACC_STRIDE; ++j) vals[j] += a[k * ACC_STRIDE + j];
    llsum += a[KDIM * ACC_STRIDE];
  }
  float z = vals[0];
  float wn = z * (1.0f / NSAMP);
  float wf = fmaxf(wn, WFLOOR);
  float S = wf;
#pragma unroll
  for (int d = 1; d < 64; d <<= 1) S += __shfl_xor(S, d, 64);
  const float sf = WFLOOR * KDIM;
  float a = (1.0f - sf) / (S - sf);
  float b = WFLOOR * (1.0f - a);
  float w = a * wf + b;
  g_w[k] = w;
  float zinv = 1.0f / z;
  float muk[LDIM], sgk[LDIM];
#pragma unroll
  for (int l = 0; l < LDIM; ++l) {
    float m = vals[1 + l] * zinv;
    float s2 = fmaxf(__builtin_fmaf(-m, m, vals[27 + l] * zinv), VFLOOR);
    muk[l] = m;
    sgk[l] = s2;
    g_mu[k * LDIM + l] = m;
    g_sig[k * LDIM + l] = s2;
  }
  if (k == 0) g_ll[0] = llsum;
  pack_row(k, w, muk, sgk, g_coef);
}

__global__ void writeout(float* __restrict__ out) {
  const int i = blockIdx.x * 256 + threadIdx.x;
  // out: w[64] | mu[64*26] | sigma[64*26*26] (diag) | ll[1]
  if (i < 64) {
    out[i] = g_w[i];
  } else if (i < 64 + KDIM * LDIM) {
    out[i] = g_mu[i - 64];
  } else if (i < 64 + KDIM * LDIM + KDIM * LDIM * LDIM) {
    int t = i - (64 + KDIM * LDIM);
    int k = t / (LDIM * LDIM);
    int r = t % (LDIM * LDIM);
    int ii = r / LDIM;
    int jj = r % LDIM;
    out[i] = (ii == jj) ? g_sig[k * LDIM + ii] : 0.f;
  } else if (i == 64 + KDIM * LDIM + KDIM * LDIM * LDIM) {
    out[i] = g_ll[0];
  }
}

extern "C" void kernel_launch(void* const* d_in, const int* in_sizes, int n_in,
                              void* d_out, int out_size, void* d_ws, size_t ws_size,
                              hipStream_t stream) {
  (void)in_sizes; (void)n_in; (void)d_ws; (void)ws_size; (void)out_size;
  const float* x   = (const float*)d_in[0];
  const float* w0  = (const float*)d_in[1];
  const float* mu0 = (const float*)d_in[2];
  const float* sg0 = (const float*)d_in[3];
  float* out = (float*)d_out;

  prep_coef<<<1, 64, 0, stream>>>(w0, mu0, sg0);
  for (int it = 0; it < NITER; ++it) {
    em_mfma<<<NBLK, 64, 0, stream>>>(x);
    reduce_partials<<<dim3(14, 8), 256, 0, stream>>>();
    finalize_k<<<1, 64, 0, stream>>>();
  }
  const int nout = 64 + KDIM * LDIM + KDIM * LDIM * LDIM + 1;  // 44993
  writeout<<<(nout + 255) / 256, 256, 0, stream>>>(out);
}